// Round 13
// baseline (181.892 us; speedup 1.0000x reference)
//
#include <hip/hip_runtime.h>
#include <math.h>

#define BB 4
#define CC 256
#define NHEAD 4
#define DH 32
#define NN 4096
#define HID 128

typedef _Float16 f16;
typedef _Float16 f16x8 __attribute__((ext_vector_type(8)));
typedef _Float16 f16x4 __attribute__((ext_vector_type(4)));
typedef float f32x4 __attribute__((ext_vector_type(4)));

#define QPRESCALE 14.42695041f
#define NSHIFT 14.42695041f

#if __has_builtin(__builtin_amdgcn_exp2f)
#define EXP2F(x) __builtin_amdgcn_exp2f(x)
#else
#define EXP2F(x) __expf((x)*0.6931471805599453f)
#endif

__device__ __forceinline__ f16x8 cvt8(const float* p) {
    float4 a = *(const float4*)p;
    float4 b = *(const float4*)(p + 4);
    f16x8 r;
    r[0] = (f16)a.x; r[1] = (f16)a.y; r[2] = (f16)a.z; r[3] = (f16)a.w;
    r[4] = (f16)b.x; r[5] = (f16)b.y; r[6] = (f16)b.z; r[7] = (f16)b.w;
    return r;
}

// ---------------- kernel 1: fused qkv GEMM + l2norm + layout ----------------
// o-tile = 128 (y = 0:q, 1:k, 2:v) so x is read 3x total (was 6x).
// Wave: 128 o x 32 i; acc c[8][2]; b-frags held, a-frag streamed.
__global__ __launch_bounds__(256) void qkv_fused(const float* __restrict__ x,
                                                 const float* __restrict__ wq,
                                                 f16* __restrict__ qh,
                                                 f16* __restrict__ kh,
                                                 f16* __restrict__ vh) {
    int wave = threadIdx.x >> 6, lane = threadIdx.x & 63;
    int quad = lane >> 4, col = lane & 15;
    int b = blockIdx.z;
    int y = blockIdx.y;                       // 0=q, 1=k, 2=v
    int o0 = y * 128;
    int i0 = blockIdx.x * 128 + wave * 32;
    const float* xb = x + (size_t)b * CC * NN;

    f32x4 c[8][2];  // [mt][nt]
#pragma unroll
    for (int mt = 0; mt < 8; mt++)
#pragma unroll
        for (int nt = 0; nt < 2; nt++) c[mt][nt] = f32x4{0.f, 0.f, 0.f, 0.f};

#pragma unroll
    for (int k0 = 0; k0 < CC; k0 += 32) {
        f16x8 bf[2];
#pragma unroll
        for (int nt = 0; nt < 2; nt++) {
            const float* xc = xb + (size_t)(k0 + quad * 8) * NN + i0 + nt * 16 + col;
#pragma unroll
            for (int j = 0; j < 8; j++) bf[nt][j] = (f16)xc[(size_t)j * NN];
        }
#pragma unroll
        for (int mt = 0; mt < 8; mt++) {
            f16x8 a = cvt8(wq + (size_t)(o0 + mt * 16 + col) * CC + k0 + quad * 8);
            c[mt][0] = __builtin_amdgcn_mfma_f32_16x16x32_f16(a, bf[0], c[mt][0], 0, 0, 0);
            c[mt][1] = __builtin_amdgcn_mfma_f32_16x16x32_f16(a, bf[1], c[mt][1], 0, 0, 0);
        }
    }

    if (y < 2) {
        f16* dst = (y == 0) ? qh : kh;
        float pre = (y == 0) ? QPRESCALE : 1.0f;
#pragma unroll
        for (int nt = 0; nt < 2; nt++) {
#pragma unroll
            for (int hh = 0; hh < 4; hh++) {  // head hh = mt {2hh, 2hh+1}
                float ss = 0.f;
#pragma unroll
                for (int m2 = 0; m2 < 2; m2++)
#pragma unroll
                    for (int r = 0; r < 4; r++) {
                        float v = c[hh * 2 + m2][nt][r];
                        ss = fmaf(v, v, ss);
                    }
                ss += __shfl_xor(ss, 16);
                ss += __shfl_xor(ss, 32);
                float inv = pre / fmaxf(sqrtf(ss), 1e-12f);
                size_t row = ((size_t)(b * 4 + hh) * NN + i0 + nt * 16 + col) * 32;
#pragma unroll
                for (int m2 = 0; m2 < 2; m2++) {
                    f16x4 st;
#pragma unroll
                    for (int r = 0; r < 4; r++) st[r] = (f16)(c[hh * 2 + m2][nt][r] * inv);
                    *(f16x4*)(dst + row + m2 * 16 + quad * 4) = st;
                }
            }
        }
    } else {
#pragma unroll
        for (int nt = 0; nt < 2; nt++) {
            int i = i0 + nt * 16 + col;
#pragma unroll
            for (int mt = 0; mt < 8; mt++) {
                int h = mt >> 1;
                int d = (mt & 1) * 16 + quad * 4;
#pragma unroll
                for (int r = 0; r < 4; r++)
                    vh[((size_t)(b * 4 + h) * 32 + d + r) * NN + i] = (f16)c[mt][nt][r];
            }
        }
    }
}

// ---------------- kernel 2: LDS-staged MFMA flash attention ----------------
// 64 q/block (4 waves x 16 q), 1024 blocks -> 4 blocks/CU, 4 waves/SIMD
// (R12 was 2/SIMD: VALU pipe starved). K/V staging identical to R12.
#define KROW 40   // 32 d + 8 pad (f16)
#define VROW 72   // 64 keys + 8 pad

struct KV32 {
    f16x8 k0, k1;
    f16x4 v0n0, v0n1, v1n0, v1n1;
};

__device__ __forceinline__ KV32 lds_frags(const f16* kl, const f16* vl,
                                          int jb, int col, int quad) {
    KV32 f;
    f.k0 = *(const f16x8*)(kl + (jb + col) * KROW + quad * 8);
    f.k1 = *(const f16x8*)(kl + (jb + 16 + col) * KROW + quad * 8);
    f.v0n0 = *(const f16x4*)(vl + col * VROW + jb + quad * 4);
    f.v0n1 = *(const f16x4*)(vl + (16 + col) * VROW + jb + quad * 4);
    f.v1n0 = *(const f16x4*)(vl + col * VROW + jb + 16 + quad * 4);
    f.v1n1 = *(const f16x4*)(vl + (16 + col) * VROW + jb + 16 + quad * 4);
    return f;
}

__device__ __forceinline__ f16x4 expblk(f32x4 s, float& lacc) {
    float p0 = EXP2F(s[0]), p1 = EXP2F(s[1]);
    float p2 = EXP2F(s[2]), p3 = EXP2F(s[3]);
    lacc += (p0 + p1) + (p2 + p3);
    f16x4 r;
    r[0] = (f16)p0; r[1] = (f16)p1; r[2] = (f16)p2; r[3] = (f16)p3;
    return r;
}

__device__ __forceinline__ void compute16(const KV32& f, f16x8 qB0,
                                          f32x4& o00, f32x4& o01, float& l0) {
    const f32x4 zs = {-NSHIFT, -NSHIFT, -NSHIFT, -NSHIFT};
    f32x4 s0 = __builtin_amdgcn_mfma_f32_16x16x32_f16(f.k0, qB0, zs, 0, 0, 0);
    f32x4 s1 = __builtin_amdgcn_mfma_f32_16x16x32_f16(f.k1, qB0, zs, 0, 0, 0);
    f16x4 p0 = expblk(s0, l0);
    f16x4 p1 = expblk(s1, l0);
    o00 = __builtin_amdgcn_mfma_f32_16x16x16f16(p0, f.v0n0, o00, 0, 0, 0);
    o01 = __builtin_amdgcn_mfma_f32_16x16x16f16(p0, f.v0n1, o01, 0, 0, 0);
    o00 = __builtin_amdgcn_mfma_f32_16x16x16f16(p1, f.v1n0, o00, 0, 0, 0);
    o01 = __builtin_amdgcn_mfma_f32_16x16x16f16(p1, f.v1n1, o01, 0, 0, 0);
}

__global__ __launch_bounds__(256, 4) void attn_mfma(const f16* __restrict__ qh,
                                                    const f16* __restrict__ kh,
                                                    const f16* __restrict__ vh,
                                                    f16* __restrict__ att16) {
    __shared__ __align__(16) f16 klds[2][64 * KROW];
    __shared__ __align__(16) f16 vlds[2][32 * VROW];
    int t = threadIdx.x;
    int wave = t >> 6, lane = t & 63;
    int quad = lane >> 4, col = lane & 15;

    // 1024 blocks; bid&7 grouping (R7-proven at exactly this grid size).
    int bid = blockIdx.x;
    int xcd = bid & 7;
    int slot = bid >> 3;             // 0..127
    int bh = xcd * 2 + (slot >> 6);  // 0..15
    int i0 = (slot & 63) * 64;
    int iw = i0 + wave * 16;

    const f16* qb = qh + (size_t)bh * NN * 32;
    const f16* kb = kh + (size_t)bh * NN * 32;
    const f16* vb = vh + (size_t)bh * 32 * NN;

    f16x8 qB0 = *(const f16x8*)(qb + (size_t)(iw + col) * 32 + quad * 8);

    f32x4 o00 = {0.f, 0.f, 0.f, 0.f}, o01 = o00;
    float l0 = 0.f;

    // staging (256 threads: K 64x32 in 16B segs, V 32x64 in 16B segs)
    int ktr = t >> 2, kts = t & 3;
    int vtr = t >> 3, vts = t & 7;

    f16x8 kr, vr;
    kr = *(const f16x8*)(kb + (size_t)(0 + ktr) * 32 + kts * 8);
    vr = *(const f16x8*)(vb + (size_t)vtr * NN + 0 + vts * 8);
    *(f16x8*)(&klds[0][0] + ktr * KROW + kts * 8) = kr;
    *(f16x8*)(&vlds[0][0] + vtr * VROW + vts * 8) = vr;
    __syncthreads();
    kr = *(const f16x8*)(kb + (size_t)(64 + ktr) * 32 + kts * 8);
    vr = *(const f16x8*)(vb + (size_t)vtr * NN + 64 + vts * 8);

    for (int tile = 0; tile < 62; tile++) {
        int buf = tile & 1;
        const f16* kl = &klds[buf][0];
        const f16* vl = &vlds[buf][0];
        KV32 f0 = lds_frags(kl, vl, 0, col, quad);
        KV32 f1 = lds_frags(kl, vl, 32, col, quad);
        compute16(f0, qB0, o00, o01, l0);
        compute16(f1, qB0, o00, o01, l0);
        *(f16x8*)(&klds[buf ^ 1][0] + ktr * KROW + kts * 8) = kr;
        *(f16x8*)(&vlds[buf ^ 1][0] + vtr * VROW + vts * 8) = vr;
        __syncthreads();
        int j0 = (tile + 2) * 64;
        kr = *(const f16x8*)(kb + (size_t)(j0 + ktr) * 32 + kts * 8);
        vr = *(const f16x8*)(vb + (size_t)vtr * NN + j0 + vts * 8);
    }
    {   // tile 62 (buf 0); kr/vr hold tile 63
        KV32 f0 = lds_frags(&klds[0][0], &vlds[0][0], 0, col, quad);
        KV32 f1 = lds_frags(&klds[0][0], &vlds[0][0], 32, col, quad);
        compute16(f0, qB0, o00, o01, l0);
        compute16(f1, qB0, o00, o01, l0);
        *(f16x8*)(&klds[1][0] + ktr * KROW + kts * 8) = kr;
        *(f16x8*)(&vlds[1][0] + vtr * VROW + vts * 8) = vr;
        __syncthreads();
    }
    {   // tile 63 (buf 1)
        KV32 f0 = lds_frags(&klds[1][0], &vlds[1][0], 0, col, quad);
        KV32 f1 = lds_frags(&klds[1][0], &vlds[1][0], 32, col, quad);
        compute16(f0, qB0, o00, o01, l0);
        compute16(f1, qB0, o00, o01, l0);
    }

    // full l per q (q = col): reduce across quads
    l0 += __shfl_xor(l0, 16); l0 += __shfl_xor(l0, 32);

    // wave-local epilogue: store f16 i-major att16[b][i][h*32+dh]
    int b = bh >> 2, h = bh & 3;
    f16* ab = att16 + (size_t)b * NN * HID + h * 32;
#pragma unroll
    for (int r = 0; r < 4; r++) {
        float inv0 = __builtin_amdgcn_rcpf(__shfl(l0, quad * 4 + r));
        size_t row0 = (size_t)(iw + quad * 4 + r) * HID;
        ab[row0 + col]      = (f16)(o00[r] * inv0);
        ab[row0 + 16 + col] = (f16)(o01[r] * inv0);
    }
}

// ---------------- kernel 3: output projection (MFMA) + bias ----------------
// o-tile 128 (2 y-blocks): att16 read 2x instead of 4x.
__global__ __launch_bounds__(256) void out_mfma(const f16* __restrict__ att16,
                                                const float* __restrict__ wo,
                                                const float* __restrict__ bo,
                                                float* __restrict__ out) {
    int wave = threadIdx.x >> 6, lane = threadIdx.x & 63;
    int quad = lane >> 4, col = lane & 15;
    int b = blockIdx.z;
    int i0 = (blockIdx.x * 4 + wave) * 32;
    int o0 = blockIdx.y * 128;
    const f16* ab = att16 + (size_t)b * NN * HID;

    f32x4 c[2][8];
#pragma unroll
    for (int it = 0; it < 2; it++)
#pragma unroll
        for (int ot = 0; ot < 8; ot++) c[it][ot] = f32x4{0.f, 0.f, 0.f, 0.f};

#pragma unroll
    for (int k0 = 0; k0 < HID; k0 += 32) {
        f16x8 a0 = *(const f16x8*)(ab + (size_t)(i0 + col) * HID + k0 + quad * 8);
        f16x8 a1 = *(const f16x8*)(ab + (size_t)(i0 + 16 + col) * HID + k0 + quad * 8);
#pragma unroll
        for (int ot = 0; ot < 8; ot++) {
            f16x8 bf = cvt8(wo + (size_t)(o0 + ot * 16 + col) * HID + k0 + quad * 8);
            c[0][ot] = __builtin_amdgcn_mfma_f32_16x16x32_f16(a0, bf, c[0][ot], 0, 0, 0);
            c[1][ot] = __builtin_amdgcn_mfma_f32_16x16x32_f16(a1, bf, c[1][ot], 0, 0, 0);
        }
    }

#pragma unroll
    for (int it = 0; it < 2; it++)
#pragma unroll
        for (int ot = 0; ot < 8; ot++) {
            int o = o0 + ot * 16 + col;
            float bias = bo[o];
            int i = i0 + it * 16 + quad * 4;
            float4 st = {c[it][ot][0] + bias, c[it][ot][1] + bias,
                         c[it][ot][2] + bias, c[it][ot][3] + bias};
            *(float4*)(out + ((size_t)b * CC + o) * NN + i) = st;
        }
}

extern "C" void kernel_launch(void* const* d_in, const int* in_sizes, int n_in,
                              void* d_out, int out_size, void* d_ws, size_t ws_size,
                              hipStream_t stream) {
    const float* x     = (const float*)d_in[0];
    const float* w_qkv = (const float*)d_in[1];
    const float* w_out = (const float*)d_in[2];
    const float* b_out = (const float*)d_in[3];
    float* out = (float*)d_out;

    char* ws = (char*)d_ws;
    f16* qh    = (f16*)(ws);                        // 4 MB
    f16* kh    = (f16*)(ws + (4u << 20));           // 4 MB
    f16* vh    = (f16*)(ws + (8u << 20));           // 4 MB
    f16* att16 = (f16*)(ws + (12u << 20));          // 4 MB

    qkv_fused<<<dim3(NN / 128, 3, BB), 256, 0, stream>>>(x, w_qkv, qh, kh, vh);
    attn_mfma<<<dim3(1024), 256, 0, stream>>>(qh, kh, vh, att16);
    out_mfma<<<dim3(NN / 128, 2, BB), 256, 0, stream>>>(att16, w_out, b_out, out);
}

// Round 14
// 173.666 us; speedup vs baseline: 1.0474x; 1.0474x over previous
//
#include <hip/hip_runtime.h>
#include <math.h>

#define BB 4
#define CC 256
#define NHEAD 4
#define DH 32
#define NN 4096
#define HID 128

typedef _Float16 f16;
typedef _Float16 f16x8 __attribute__((ext_vector_type(8)));
typedef _Float16 f16x4 __attribute__((ext_vector_type(4)));
typedef float f32x4 __attribute__((ext_vector_type(4)));

#define QPRESCALE 14.42695041f
#define NSHIFT 14.42695041f

#if __has_builtin(__builtin_amdgcn_exp2f)
#define EXP2F(x) __builtin_amdgcn_exp2f(x)
#else
#define EXP2F(x) __expf((x)*0.6931471805599453f)
#endif

__device__ __forceinline__ f16x8 cvt8(const float* p) {
    float4 a = *(const float4*)p;
    float4 b = *(const float4*)(p + 4);
    f16x8 r;
    r[0] = (f16)a.x; r[1] = (f16)a.y; r[2] = (f16)a.z; r[3] = (f16)a.w;
    r[4] = (f16)b.x; r[5] = (f16)b.y; r[6] = (f16)b.z; r[7] = (f16)b.w;
    return r;
}

// ---------------- kernel 1: fused qkv GEMM + l2norm + layout ----------------
__global__ __launch_bounds__(256) void qkv_fused(const float* __restrict__ x,
                                                 const float* __restrict__ wq,
                                                 f16* __restrict__ qh,
                                                 f16* __restrict__ kh,
                                                 f16* __restrict__ vh) {
    int wave = threadIdx.x >> 6, lane = threadIdx.x & 63;
    int quad = lane >> 4, col = lane & 15;
    int b = blockIdx.z;
    int y = blockIdx.y;                       // 0=q, 1=k, 2=v
    int o0 = y * 128;
    int i0 = blockIdx.x * 128 + wave * 32;
    const float* xb = x + (size_t)b * CC * NN;

    f32x4 c[8][2];
#pragma unroll
    for (int mt = 0; mt < 8; mt++)
#pragma unroll
        for (int nt = 0; nt < 2; nt++) c[mt][nt] = f32x4{0.f, 0.f, 0.f, 0.f};

#pragma unroll
    for (int k0 = 0; k0 < CC; k0 += 32) {
        f16x8 bf[2];
#pragma unroll
        for (int nt = 0; nt < 2; nt++) {
            const float* xc = xb + (size_t)(k0 + quad * 8) * NN + i0 + nt * 16 + col;
#pragma unroll
            for (int j = 0; j < 8; j++) bf[nt][j] = (f16)xc[(size_t)j * NN];
        }
#pragma unroll
        for (int mt = 0; mt < 8; mt++) {
            f16x8 a = cvt8(wq + (size_t)(o0 + mt * 16 + col) * CC + k0 + quad * 8);
            c[mt][0] = __builtin_amdgcn_mfma_f32_16x16x32_f16(a, bf[0], c[mt][0], 0, 0, 0);
            c[mt][1] = __builtin_amdgcn_mfma_f32_16x16x32_f16(a, bf[1], c[mt][1], 0, 0, 0);
        }
    }

    if (y < 2) {
        f16* dst = (y == 0) ? qh : kh;
        float pre = (y == 0) ? QPRESCALE : 1.0f;
#pragma unroll
        for (int nt = 0; nt < 2; nt++) {
#pragma unroll
            for (int hh = 0; hh < 4; hh++) {
                float ss = 0.f;
#pragma unroll
                for (int m2 = 0; m2 < 2; m2++)
#pragma unroll
                    for (int r = 0; r < 4; r++) {
                        float v = c[hh * 2 + m2][nt][r];
                        ss = fmaf(v, v, ss);
                    }
                ss += __shfl_xor(ss, 16);
                ss += __shfl_xor(ss, 32);
                float inv = pre / fmaxf(sqrtf(ss), 1e-12f);
                size_t row = ((size_t)(b * 4 + hh) * NN + i0 + nt * 16 + col) * 32;
#pragma unroll
                for (int m2 = 0; m2 < 2; m2++) {
                    f16x4 st;
#pragma unroll
                    for (int r = 0; r < 4; r++) st[r] = (f16)(c[hh * 2 + m2][nt][r] * inv);
                    *(f16x4*)(dst + row + m2 * 16 + quad * 4) = st;
                }
            }
        }
    } else {
#pragma unroll
        for (int nt = 0; nt < 2; nt++) {
            int i = i0 + nt * 16 + col;
#pragma unroll
            for (int mt = 0; mt < 8; mt++) {
                int h = mt >> 1;
                int d = (mt & 1) * 16 + quad * 4;
#pragma unroll
                for (int r = 0; r < 4; r++)
                    vh[((size_t)(b * 4 + h) * 32 + d + r) * NN + i] = (f16)c[mt][nt][r];
            }
        }
    }
}

// ---------------- kernel 2: LDS-staged flash attention, 2-way key split -----
// R12 shape (128 q/block, 4 waves x 32 q) + key-split across blocks:
// 1024 blocks x 2048 keys. Total staging volume == R12 (R13 lesson: scale
// block count by splitting keys, not q). l computed on the MFMA pipe via
// P x ones (removes 12 VALU adds/compute32 and all epilogue shuffles).
#define KROW 40
#define VROW 72
#define KSPLIT 2048
#define NTILE (KSPLIT / 64)

struct KV32 {
    f16x8 k0, k1;
    f16x4 v0n0, v0n1, v1n0, v1n1;
};

__device__ __forceinline__ KV32 lds_frags(const f16* kl, const f16* vl,
                                          int jb, int col, int quad) {
    KV32 f;
    f.k0 = *(const f16x8*)(kl + (jb + col) * KROW + quad * 8);
    f.k1 = *(const f16x8*)(kl + (jb + 16 + col) * KROW + quad * 8);
    f.v0n0 = *(const f16x4*)(vl + col * VROW + jb + quad * 4);
    f.v0n1 = *(const f16x4*)(vl + (16 + col) * VROW + jb + quad * 4);
    f.v1n0 = *(const f16x4*)(vl + col * VROW + jb + 16 + quad * 4);
    f.v1n1 = *(const f16x4*)(vl + (16 + col) * VROW + jb + 16 + quad * 4);
    return f;
}

__device__ __forceinline__ f16x4 expblk(f32x4 s) {
    f16x4 r;
    r[0] = (f16)EXP2F(s[0]); r[1] = (f16)EXP2F(s[1]);
    r[2] = (f16)EXP2F(s[2]); r[3] = (f16)EXP2F(s[3]);
    return r;
}

__device__ __forceinline__ void compute32(const KV32& f, f16x8 qB0, f16x8 qB1,
                                          f32x4& o00, f32x4& o01,
                                          f32x4& o10, f32x4& o11,
                                          f32x4& la0, f32x4& la1, f16x4 vones) {
    const f32x4 zs = {-NSHIFT, -NSHIFT, -NSHIFT, -NSHIFT};
    f32x4 s00 = __builtin_amdgcn_mfma_f32_16x16x32_f16(f.k0, qB0, zs, 0, 0, 0);
    f32x4 s10 = __builtin_amdgcn_mfma_f32_16x16x32_f16(f.k0, qB1, zs, 0, 0, 0);
    f32x4 s01 = __builtin_amdgcn_mfma_f32_16x16x32_f16(f.k1, qB0, zs, 0, 0, 0);
    f32x4 s11 = __builtin_amdgcn_mfma_f32_16x16x32_f16(f.k1, qB1, zs, 0, 0, 0);
    f16x4 p00 = expblk(s00);
    f16x4 p10 = expblk(s10);
    f16x4 p01 = expblk(s01);
    f16x4 p11 = expblk(s11);
    o00 = __builtin_amdgcn_mfma_f32_16x16x16f16(p00, f.v0n0, o00, 0, 0, 0);
    o01 = __builtin_amdgcn_mfma_f32_16x16x16f16(p00, f.v0n1, o01, 0, 0, 0);
    la0 = __builtin_amdgcn_mfma_f32_16x16x16f16(p00, vones, la0, 0, 0, 0);
    o10 = __builtin_amdgcn_mfma_f32_16x16x16f16(p10, f.v0n0, o10, 0, 0, 0);
    o11 = __builtin_amdgcn_mfma_f32_16x16x16f16(p10, f.v0n1, o11, 0, 0, 0);
    la1 = __builtin_amdgcn_mfma_f32_16x16x16f16(p10, vones, la1, 0, 0, 0);
    o00 = __builtin_amdgcn_mfma_f32_16x16x16f16(p01, f.v1n0, o00, 0, 0, 0);
    o01 = __builtin_amdgcn_mfma_f32_16x16x16f16(p01, f.v1n1, o01, 0, 0, 0);
    la0 = __builtin_amdgcn_mfma_f32_16x16x16f16(p01, vones, la0, 0, 0, 0);
    o10 = __builtin_amdgcn_mfma_f32_16x16x16f16(p11, f.v1n0, o10, 0, 0, 0);
    o11 = __builtin_amdgcn_mfma_f32_16x16x16f16(p11, f.v1n1, o11, 0, 0, 0);
    la1 = __builtin_amdgcn_mfma_f32_16x16x16f16(p11, vones, la1, 0, 0, 0);
}

__global__ __launch_bounds__(256, 4) void attn_mfma(const f16* __restrict__ qh,
                                                    const f16* __restrict__ kh,
                                                    const f16* __restrict__ vh,
                                                    float* __restrict__ opart,
                                                    float* __restrict__ lpart) {
    __shared__ __align__(16) f16 klds[2][64 * KROW];
    __shared__ __align__(16) f16 vlds[2][32 * VROW];
    int t = threadIdx.x;
    int wave = t >> 6, lane = t & 63;
    int quad = lane >> 4, col = lane & 15;

    // 1024 blocks; bid&7 XCD grouping (R7/R10-proven); per xcd: 2 bh x 2 ks x 32 i-slots.
    int bid = blockIdx.x;
    int xcd = bid & 7;
    int slot = bid >> 3;             // 0..127
    int bh = xcd * 2 + (slot >> 6);  // 0..15
    int rem = slot & 63;
    int ks = rem >> 5;               // key-split half
    int i0 = (rem & 31) * 128;
    int iw = i0 + wave * 32;
    int jbase = ks * KSPLIT;

    const f16* qb = qh + (size_t)bh * NN * 32;
    const f16* kb = kh + (size_t)bh * NN * 32;
    const f16* vb = vh + (size_t)bh * 32 * NN;

    f16x8 qB0 = *(const f16x8*)(qb + (size_t)(iw + col) * 32 + quad * 8);
    f16x8 qB1 = *(const f16x8*)(qb + (size_t)(iw + 16 + col) * 32 + quad * 8);

    f32x4 o00 = {0.f, 0.f, 0.f, 0.f}, o01 = o00, o10 = o00, o11 = o00;
    f32x4 la0 = o00, la1 = o00;
    f16x4 vones = {(f16)1.f, (f16)1.f, (f16)1.f, (f16)1.f};

    int ktr = t >> 2, kts = t & 3;
    int vtr = t >> 3, vts = t & 7;

    f16x8 kr, vr;
    kr = *(const f16x8*)(kb + (size_t)(jbase + ktr) * 32 + kts * 8);
    vr = *(const f16x8*)(vb + (size_t)vtr * NN + jbase + vts * 8);
    *(f16x8*)(&klds[0][0] + ktr * KROW + kts * 8) = kr;
    *(f16x8*)(&vlds[0][0] + vtr * VROW + vts * 8) = vr;
    __syncthreads();
    kr = *(const f16x8*)(kb + (size_t)(jbase + 64 + ktr) * 32 + kts * 8);
    vr = *(const f16x8*)(vb + (size_t)vtr * NN + jbase + 64 + vts * 8);

    for (int tile = 0; tile < NTILE - 2; tile++) {
        int buf = tile & 1;
        const f16* kl = &klds[buf][0];
        const f16* vl = &vlds[buf][0];
        KV32 f0 = lds_frags(kl, vl, 0, col, quad);
        KV32 f1 = lds_frags(kl, vl, 32, col, quad);
        compute32(f0, qB0, qB1, o00, o01, o10, o11, la0, la1, vones);
        compute32(f1, qB0, qB1, o00, o01, o10, o11, la0, la1, vones);
        *(f16x8*)(&klds[buf ^ 1][0] + ktr * KROW + kts * 8) = kr;
        *(f16x8*)(&vlds[buf ^ 1][0] + vtr * VROW + vts * 8) = vr;
        __syncthreads();
        int j0 = jbase + (tile + 2) * 64;
        kr = *(const f16x8*)(kb + (size_t)(j0 + ktr) * 32 + kts * 8);
        vr = *(const f16x8*)(vb + (size_t)vtr * NN + j0 + vts * 8);
    }
    {   // tile NTILE-2 (buf 0); kr/vr hold last tile
        KV32 f0 = lds_frags(&klds[0][0], &vlds[0][0], 0, col, quad);
        KV32 f1 = lds_frags(&klds[0][0], &vlds[0][0], 32, col, quad);
        compute32(f0, qB0, qB1, o00, o01, o10, o11, la0, la1, vones);
        compute32(f1, qB0, qB1, o00, o01, o10, o11, la0, la1, vones);
        *(f16x8*)(&klds[1][0] + ktr * KROW + kts * 8) = kr;
        *(f16x8*)(&vlds[1][0] + vtr * VROW + vts * 8) = vr;
        __syncthreads();
    }
    {   // last tile (buf 1)
        KV32 f0 = lds_frags(&klds[1][0], &vlds[1][0], 0, col, quad);
        KV32 f1 = lds_frags(&klds[1][0], &vlds[1][0], 32, col, quad);
        compute32(f0, qB0, qB1, o00, o01, o10, o11, la0, la1, vones);
        compute32(f1, qB0, qB1, o00, o01, o10, o11, la0, la1, vones);
    }

    // partial write: la rows coincide with O rows (both C-layout) — no shuffles.
    float* op = opart + (size_t)(ks * 16 + bh) * NN * 32;
    float* lp = lpart + (size_t)(ks * 16 + bh) * NN;
#pragma unroll
    for (int r = 0; r < 4; r++) {
        int q0 = iw + quad * 4 + r;
        int q1 = iw + 16 + quad * 4 + r;
        op[(size_t)q0 * 32 + col]      = o00[r];
        op[(size_t)q0 * 32 + 16 + col] = o01[r];
        op[(size_t)q1 * 32 + col]      = o10[r];
        op[(size_t)q1 * 32 + 16 + col] = o11[r];
        if (col == 0) { lp[q0] = la0[r]; lp[q1] = la1[r]; }
    }
}

// ---------------- kernel 2b: combine key-split halves ----------------
__global__ __launch_bounds__(256) void combine(const float* __restrict__ opart,
                                               const float* __restrict__ lpart,
                                               f16* __restrict__ att16) {
    int idx = blockIdx.x * 256 + threadIdx.x;   // over 16*4096
    int bh = idx >> 12, i = idx & 4095;
    const float* p0 = opart + ((size_t)bh * NN + i) * 32;
    const float* p1 = opart + ((size_t)(16 + bh) * NN + i) * 32;
    float l = lpart[(size_t)bh * NN + i] + lpart[(size_t)(16 + bh) * NN + i];
    float inv = 1.0f / l;
    int b = bh >> 2, h = bh & 3;
    f16* dst = att16 + ((size_t)b * NN + i) * HID + h * 32;
#pragma unroll
    for (int g = 0; g < 4; g++) {
        float4 a0 = *(const float4*)(p0 + g * 8);
        float4 a1 = *(const float4*)(p0 + g * 8 + 4);
        float4 b0 = *(const float4*)(p1 + g * 8);
        float4 b1 = *(const float4*)(p1 + g * 8 + 4);
        f16x8 o8;
        o8[0] = (f16)((a0.x + b0.x) * inv); o8[1] = (f16)((a0.y + b0.y) * inv);
        o8[2] = (f16)((a0.z + b0.z) * inv); o8[3] = (f16)((a0.w + b0.w) * inv);
        o8[4] = (f16)((a1.x + b1.x) * inv); o8[5] = (f16)((a1.y + b1.y) * inv);
        o8[6] = (f16)((a1.z + b1.z) * inv); o8[7] = (f16)((a1.w + b1.w) * inv);
        *(f16x8*)(dst + g * 8) = o8;
    }
}

// ---------------- kernel 3: output projection (MFMA) + bias ----------------
__global__ __launch_bounds__(256) void out_mfma(const f16* __restrict__ att16,
                                                const float* __restrict__ wo,
                                                const float* __restrict__ bo,
                                                float* __restrict__ out) {
    int wave = threadIdx.x >> 6, lane = threadIdx.x & 63;
    int quad = lane >> 4, col = lane & 15;
    int b = blockIdx.z;
    int i0 = (blockIdx.x * 4 + wave) * 32;
    int o0 = blockIdx.y * 128;
    const f16* ab = att16 + (size_t)b * NN * HID;

    f32x4 c[2][8];
#pragma unroll
    for (int it = 0; it < 2; it++)
#pragma unroll
        for (int ot = 0; ot < 8; ot++) c[it][ot] = f32x4{0.f, 0.f, 0.f, 0.f};

#pragma unroll
    for (int k0 = 0; k0 < HID; k0 += 32) {
        f16x8 a0 = *(const f16x8*)(ab + (size_t)(i0 + col) * HID + k0 + quad * 8);
        f16x8 a1 = *(const f16x8*)(ab + (size_t)(i0 + 16 + col) * HID + k0 + quad * 8);
#pragma unroll
        for (int ot = 0; ot < 8; ot++) {
            f16x8 bf = cvt8(wo + (size_t)(o0 + ot * 16 + col) * HID + k0 + quad * 8);
            c[0][ot] = __builtin_amdgcn_mfma_f32_16x16x32_f16(a0, bf, c[0][ot], 0, 0, 0);
            c[1][ot] = __builtin_amdgcn_mfma_f32_16x16x32_f16(a1, bf, c[1][ot], 0, 0, 0);
        }
    }

#pragma unroll
    for (int it = 0; it < 2; it++)
#pragma unroll
        for (int ot = 0; ot < 8; ot++) {
            int o = o0 + ot * 16 + col;
            float bias = bo[o];
            int i = i0 + it * 16 + quad * 4;
            float4 st = {c[it][ot][0] + bias, c[it][ot][1] + bias,
                         c[it][ot][2] + bias, c[it][ot][3] + bias};
            *(float4*)(out + ((size_t)b * CC + o) * NN + i) = st;
        }
}

extern "C" void kernel_launch(void* const* d_in, const int* in_sizes, int n_in,
                              void* d_out, int out_size, void* d_ws, size_t ws_size,
                              hipStream_t stream) {
    const float* x     = (const float*)d_in[0];
    const float* w_qkv = (const float*)d_in[1];
    const float* w_out = (const float*)d_in[2];
    const float* b_out = (const float*)d_in[3];
    float* out = (float*)d_out;

    char* ws = (char*)d_ws;
    f16* qh      = (f16*)(ws);                   // 4 MB
    f16* kh      = (f16*)(ws + (4u << 20));      // 4 MB
    f16* vh      = (f16*)(ws + (8u << 20));      // 4 MB
    f16* att16   = (f16*)(ws + (12u << 20));     // 4 MB
    float* opart = (float*)(ws + (16u << 20));   // 16 MB
    float* lpart = (float*)(ws + (32u << 20));   // 512 KB

    qkv_fused<<<dim3(NN / 128, 3, BB), 256, 0, stream>>>(x, w_qkv, qh, kh, vh);
    attn_mfma<<<dim3(1024), 256, 0, stream>>>(qh, kh, vh, opart, lpart);
    combine<<<dim3(16 * NN / 256), 256, 0, stream>>>(opart, lpart, att16);
    out_mfma<<<dim3(NN / 128, 2, BB), 256, 0, stream>>>(att16, w_out, b_out, out);
}